// Round 14
// baseline (762.634 us; speedup 1.0000x reference)
//
#include <hip/hip_runtime.h>

typedef unsigned short u16;
typedef unsigned int u32;
typedef __attribute__((ext_vector_type(4))) float f32x4;
typedef __attribute__((ext_vector_type(8))) short bf16x8;

#define TOK 32768      // B*N tokens
#define KP  832        // padded 784 (13*64) K-dim
#define NKT 13         // K-tiles of 64
#define DHP 416        // padded 392 (13*32)
#define DHPV 512       // padded 392 rows for V^T
#define NQKV 2560      // padded 2352 (10*256) rows of qkv_w

static __device__ __forceinline__ float bf2f(u16 u){ u32 v = ((u32)u)<<16; return __builtin_bit_cast(float, v); }
static __device__ __forceinline__ u16 f2bf(float f){
  u32 x = __builtin_bit_cast(u32, f);
  u32 r = (x + 0x7fffu + ((x>>16)&1u)) >> 16;   // RNE
  return (u16)r;
}
static __device__ __forceinline__ void gload16(const void* g, void* l){
  __builtin_amdgcn_global_load_lds((const __attribute__((address_space(1))) void*)g,
                                   (__attribute__((address_space(3))) void*)l, 16, 0, 0);
}
static __device__ __forceinline__ float wave_red_sum(float v){
  #pragma unroll
  for (int o = 32; o > 0; o >>= 1) v += __shfl_xor(v, o, 64);
  return v;
}

// ---------------- weight fp32 -> bf16 with zero padding to [*, KP] ----------------
__global__ __launch_bounds__(256) void wconv_k(const float* __restrict__ src, u16* __restrict__ dst,
                                               int srcR, long long total){
  long long i = (long long)blockIdx.x*256 + threadIdx.x;
  if (i >= total) return;
  int r = (int)(i / KP), c = (int)(i % KP);
  float v = (r < srcR && c < 784) ? src[(long long)r*784 + c] : 0.f;
  dst[i] = f2bf(v);
}

// ---------------- LayerNorm(x fp32) -> bf16 padded [TOK, KP] ----------------
__global__ __launch_bounds__(256) void ln1_k(const float* __restrict__ x, const float* __restrict__ w,
                                             const float* __restrict__ b, u16* __restrict__ out){
  const int tid = threadIdx.x;
  const long long row = blockIdx.x;
  const float* xr = x + row*784;
  float v[4]; float s = 0.f, ss = 0.f;
  #pragma unroll
  for (int i = 0; i < 4; i++){ int c = tid + i*256; float t = (c < 784) ? xr[c] : 0.f; v[i] = t; s += t; ss += t*t; }
  __shared__ float red[8];
  s = wave_red_sum(s); ss = wave_red_sum(ss);
  if ((tid & 63) == 0){ red[tid>>6] = s; red[4 + (tid>>6)] = ss; }
  __syncthreads();
  float S  = red[0]+red[1]+red[2]+red[3];
  float SS = red[4]+red[5]+red[6]+red[7];
  float mean = S * (1.f/784.f);
  float var  = SS * (1.f/784.f) - mean*mean;
  float rstd = rsqrtf(var + 1e-5f);
  u16* orow = out + row*KP;
  #pragma unroll
  for (int i = 0; i < 4; i++){
    int c = tid + i*256;
    if (c < KP){
      u16 o = 0;
      if (c < 784) o = f2bf((v[i]-mean)*rstd*w[c] + b[c]);
      orow[c] = o;
    }
  }
}

// ---------------- LayerNorm(attnout bf16) + hardswish -> bf16 padded [TOK, KP] ----------------
__global__ __launch_bounds__(256) void ln2hs_k(const u16* __restrict__ a, const float* __restrict__ w,
                                               const float* __restrict__ b, u16* __restrict__ out){
  const int tid = threadIdx.x;
  const long long row = blockIdx.x;
  const u16* ar = a + row*784;
  float v[4]; float s = 0.f, ss = 0.f;
  #pragma unroll
  for (int i = 0; i < 4; i++){ int c = tid + i*256; float t = (c < 784) ? bf2f(ar[c]) : 0.f; v[i] = t; s += t; ss += t*t; }
  __shared__ float red[8];
  s = wave_red_sum(s); ss = wave_red_sum(ss);
  if ((tid & 63) == 0){ red[tid>>6] = s; red[4 + (tid>>6)] = ss; }
  __syncthreads();
  float S  = red[0]+red[1]+red[2]+red[3];
  float SS = red[4]+red[5]+red[6]+red[7];
  float mean = S * (1.f/784.f);
  float var  = SS * (1.f/784.f) - mean*mean;
  float rstd = rsqrtf(var + 1e-5f);
  u16* orow = out + row*KP;
  #pragma unroll
  for (int i = 0; i < 4; i++){
    int c = tid + i*256;
    if (c < KP){
      u16 o = 0;
      if (c < 784){
        float y = (v[i]-mean)*rstd*w[c] + b[c];
        y = y * fminf(fmaxf(y + 3.f, 0.f), 6.f) * (1.f/6.f);   // hardswish
        o = f2bf(y);
      }
      orow[c] = o;
    }
  }
}

// ---------------- compute L2-norm factors for Q (x sqrt(scale)) and K; zero row pads ----------------
// READ-ONLY on the 392 real elements; writes facQ/facK (fp32) + zeroes d=392..415 (24 u16/row).
// Replaces the old in-place l2norm rewrite (halves this pass's HBM traffic).
__global__ __launch_bounds__(256) void norm_k(u16* __restrict__ Q, u16* __restrict__ Kb,
                                              const float* __restrict__ scale,
                                              float* __restrict__ facQ, float* __restrict__ facK){
  const int lane = threadIdx.x & 63, wv = threadIdx.x >> 6;
  const long long rid = (long long)blockIdx.x*4 + wv;     // 131072 rows: Q then K
  const bool isK = rid >= 65536;
  const long long idx = isK ? rid - 65536 : rid;
  u16* base = (isK ? Kb : Q) + idx*DHP;
  // chunks of 4 bf16: 0..97 real (d<392)
  uint2 t0 = *(const uint2*)(base + lane*4);
  int ch1 = lane + 64;
  uint2 t1 = (ch1 < 98) ? *(const uint2*)(base + ch1*4) : make_uint2(0u,0u);
  float ssq = 0.f;
  u32 c0[2] = {t0.x, t0.y}, c1[2] = {t1.x, t1.y};
  #pragma unroll
  for (int j = 0; j < 4; j++){
    float a = bf2f((u16)(c0[j>>1] >> ((j&1)*16)));
    ssq += a*a;
  }
  if (ch1 < 98){
    #pragma unroll
    for (int j = 0; j < 4; j++){
      float a = bf2f((u16)(c1[j>>1] >> ((j&1)*16)));
      ssq += a*a;
    }
  }
  ssq = wave_red_sum(ssq);
  if (lane == 0){
    float fac = 1.f / fmaxf(sqrtf(ssq), 1e-12f);
    if (isK) facK[idx] = fac;
    else     facQ[idx] = fac * sqrtf(scale[(int)((idx >> 10) & 1)]);
  }
  // zero pads d=392..415 (reduction dim in QK^T -> must be exactly zero)
  if (lane < 12) *(u32*)(base + 392 + lane*2) = 0u;
}

// =======================================================================================
// Fused attention v7: R11 staged structure + in-kernel l2norm factors.
// sacc is scaled by facQ[q]*facK[kv] BEFORE exp (algebraically exact: l2norm commutes
// through the dot product). facQ read via volatile ptr to avoid 16 hoisted VGPRs.
// =======================================================================================
__global__ __launch_bounds__(512, 2) void attn_k(const u16* __restrict__ Qb, const u16* __restrict__ Kb,
    const u16* __restrict__ Vtb, const float* __restrict__ facQ, const float* __restrict__ facK,
    u16* __restrict__ att)
{
  __shared__ u16 smem[40960];      // slots 0..2 at 0/8192/16384 (16 KB each); Pbuf at 24576 (32 KB)
  u16* Pbuf = smem + 24576;

  const int tid = threadIdx.x, lane = tid & 63, wid = tid >> 6;
  const int wq  = wid >> 2, kvw = wid & 3;     // phase A: 2 q-halves(64) x 4 kv(32)
  const int dw  = wid >> 2, qw  = wid & 3;     // phase B: 2 d(112) x 4 q(32)

  const int lin = (int)blockIdx.x;
  const int bh = (lin & 7)*8 + (lin >> 6);
  const int qt = (lin >> 3) & 7;

  const u16* Qp = Qb  + ((long long)bh*1024 + (long long)qt*128)*DHP;
  const u16* Kp = Kb  + (long long)bh*1024*DHP;
  const u16* Vp = Vtb + (long long)bh*DHPV*1024;
  const volatile float* fQv = facQ + (long long)bh*1024 + qt*128;   // volatile: no VGPR hoist
  const float* fKb = facK + (long long)bh*1024;

  const int srow = tid >> 2;
  const int scol = (((tid & 3) ^ ((srow >> 1) & 3)) << 3);
  const int s2   = tid + 512;
  const int r2   = s2 >> 2;
  const int c2   = (((s2 & 3) ^ ((r2 >> 1) & 3)) << 3);

  int offq[4], offk[2], offv[7];
  #pragma unroll
  for (int m = 0; m < 4; m++){
    int r = wq*64 + m*16 + (lane & 15);
    offq[m] = r*32 + ((((lane>>4) ^ (r>>1)) & 3) << 3);
  }
  #pragma unroll
  for (int n = 0; n < 2; n++){
    int r = kvw*32 + n*16 + (lane & 15);
    offk[n] = 4096 + r*32 + ((((lane>>4) ^ (r>>1)) & 3) << 3);
  }
  #pragma unroll
  for (int m = 0; m < 7; m++){
    int r = dw*112 + m*16 + (lane & 15);
    offv[m] = r*32 + ((((lane>>4) ^ (r>>1)) & 3) << 3);
  }

  auto stageA = [&](int ck, int t, int buf){
    u16* rb = smem + buf*8192;
    gload16(Qp + (long long)srow*DHP + t*32 + scol,            rb + tid*8);
    gload16(Kp + (long long)(ck*128 + srow)*DHP + t*32 + scol, rb + 4096 + tid*8);
  };
  auto stageV = [&](int ck, int ms, int buf){
    u16* rb = smem + buf*8192;
    const int h = ms >> 2, s = ms & 3;
    const u16* src = Vp + (long long)(h*224)*1024 + ck*128 + s*32;
    gload16(src + (long long)srow*1024 + scol, rb + tid*8);
    gload16(src + (long long)r2*1024  + c2,   rb + s2*8);
  };

  f32x4 oacc[2][7][2];
  #pragma unroll
  for (int h = 0; h < 2; h++)
    #pragma unroll
    for (int m = 0; m < 7; m++)
      #pragma unroll
      for (int n = 0; n < 2; n++) oacc[h][m][n] = f32x4{0.f,0.f,0.f,0.f};
  float rs_r[16];
  #pragma unroll
  for (int i = 0; i < 16; i++) rs_r[i] = 0.f;

  for (int ck = 0; ck < 8; ++ck){
    // ---------------- phase A: S = Q @ K^T (13 steps, ring-3, lookahead-2) ----------------
    stageA(ck, 0, 0); stageA(ck, 1, 1);
    asm volatile("s_waitcnt vmcnt(2)" ::: "memory");
    __builtin_amdgcn_s_barrier();
    f32x4 sacc[4][2];
    #pragma unroll
    for (int m = 0; m < 4; m++)
      #pragma unroll
      for (int n = 0; n < 2; n++) sacc[m][n] = f32x4{0.f,0.f,0.f,0.f};

    for (int t = 0; t < 13; ++t){
      if (t + 2 < 13) stageA(ck, t+2, (t+2)%3);
      const u16* ra = smem + (t%3)*8192;
      bf16x8 aq[4], bk[2];
      #pragma unroll
      for (int m = 0; m < 4; m++) aq[m] = *(const bf16x8*)(ra + offq[m]);
      #pragma unroll
      for (int n = 0; n < 2; n++) bk[n] = *(const bf16x8*)(ra + offk[n]);
      __builtin_amdgcn_s_setprio(1);
      #pragma unroll
      for (int m = 0; m < 4; m++)
        #pragma unroll
        for (int n = 0; n < 2; n++)
          sacc[m][n] = __builtin_amdgcn_mfma_f32_16x16x32_bf16(aq[m], bk[n], sacc[m][n], 0, 0, 0);
      __builtin_amdgcn_s_setprio(0);
      if (t + 2 < 13)      asm volatile("s_waitcnt vmcnt(2)" ::: "memory");
      else if (t + 1 < 13) asm volatile("s_waitcnt vmcnt(0)" ::: "memory");
      if (t + 1 < 13) __builtin_amdgcn_s_barrier();
    }
    __builtin_amdgcn_s_barrier();   // all waves done reading ring

    // -------- transition: issue V0,V1 stages, then P = exp(fq*fk*S) -> Pbuf + rowsum --------
    stageV(ck, 0, 0); stageV(ck, 1, 1);
    const float fk0 = fKb[ck*128 + kvw*32 +      (lane & 15)];
    const float fk1 = fKb[ck*128 + kvw*32 + 16 + (lane & 15)];
    #pragma unroll
    for (int m = 0; m < 4; m++){
      #pragma unroll
      for (int i = 0; i < 4; i++){
        const int q = wq*64 + m*16 + (lane>>4)*4 + i;
        const float fq = fQv[q];
        float a = 0.f;
        #pragma unroll
        for (int n = 0; n < 2; n++){
          const int kv = kvw*32 + n*16 + (lane & 15);
          u16 pb = f2bf(__expf(sacc[m][n][i] * fq * (n ? fk1 : fk0)));
          Pbuf[q*128 + (((kv>>3) ^ (q&15)) << 3) + (kv&7)] = pb;
          a += bf2f(pb);
        }
        rs_r[m*4+i] += a;
      }
    }
    asm volatile("s_waitcnt vmcnt(2) lgkmcnt(0)" ::: "memory");   // V0 ready, P visible
    __builtin_amdgcn_s_barrier();

    // ---------------- phase B: O^T += VT @ P^T (8 steps, ring-3, lookahead-2) ----------------
    #pragma unroll
    for (int ms = 0; ms < 8; ++ms){
      if (ms + 2 < 8) stageV(ck, ms+2, (ms+2)%3);
      const u16* vb = smem + (ms%3)*8192;
      const int s = ms & 3;
      const int h = ms >> 2;
      bf16x8 av[7], bp[2];
      #pragma unroll
      for (int m = 0; m < 7; m++) av[m] = *(const bf16x8*)(vb + offv[m]);
      #pragma unroll
      for (int n = 0; n < 2; n++){
        const int q = qw*32 + n*16 + (lane & 15);
        const int cc = s*4 + (lane>>4);
        bp[n] = *(const bf16x8*)(Pbuf + q*128 + ((cc ^ (q&15)) << 3));
      }
      __builtin_amdgcn_s_setprio(1);
      #pragma unroll
      for (int m = 0; m < 7; m++)
        #pragma unroll
        for (int n = 0; n < 2; n++)
          oacc[h][m][n] = __builtin_amdgcn_mfma_f32_16x16x32_bf16(av[m], bp[n], oacc[h][m][n], 0, 0, 0);
      __builtin_amdgcn_s_setprio(0);
      if (ms + 2 < 8)      asm volatile("s_waitcnt vmcnt(2)" ::: "memory");
      else if (ms + 1 < 8) asm volatile("s_waitcnt vmcnt(0)" ::: "memory");
      if (ms + 1 < 8) __builtin_amdgcn_s_barrier();
    }
    __builtin_amdgcn_s_barrier();   // ring + Pbuf free before next chunk's phase A
  }

  float* rsL = (float*)&smem[0];   // [128][4]
  float* rsT = rsL + 512;          // [128]
  #pragma unroll
  for (int m = 0; m < 4; m++){
    #pragma unroll
    for (int i = 0; i < 4; i++){
      float v = rs_r[m*4+i];
      v += __shfl_xor(v, 1, 64); v += __shfl_xor(v, 2, 64);
      v += __shfl_xor(v, 4, 64); v += __shfl_xor(v, 8, 64);
      if ((lane & 15) == 0) rsL[(wq*64 + m*16 + (lane>>4)*4 + i)*4 + kvw] = v;
    }
  }
  __syncthreads();
  if (tid < 128) rsT[tid] = 1.f/(rsL[tid*4]+rsL[tid*4+1]+rsL[tid*4+2]+rsL[tid*4+3]);
  __syncthreads();
  const int b = bh >> 1, hh = bh & 1;
  #pragma unroll
  for (int h = 0; h < 2; h++){
    #pragma unroll
    for (int n = 0; n < 2; n++){
      const int q = qw*32 + n*16 + (lane & 15);
      const float rinv = rsT[q];
      u16* arw = att + ((long long)(b*1024 + qt*128 + q))*784 + hh*392;
      #pragma unroll
      for (int m = 0; m < 7; m++){
        const int d0 = h*224 + dw*112 + m*16 + (lane>>4)*4;
        if (d0 < 392){
          u16 a0 = f2bf(oacc[h][m][n][0]*rinv), a1 = f2bf(oacc[h][m][n][1]*rinv);
          u16 a2 = f2bf(oacc[h][m][n][2]*rinv), a3 = f2bf(oacc[h][m][n][3]*rinv);
          *(u32*)(arw + d0)     = (u32)a0 | ((u32)a1 << 16);
          *(u32*)(arw + d0 + 2) = (u32)a2 | ((u32)a3 << 16);
        }
      }
    }
  }
}

// =======================================================================================
// GEMM v7 (frozen): 4-phase K-split loop + coalesced QKV epilogue.
// EPI 0: QKV  4: FFN+hs+residual  5: fp32 out
// =======================================================================================
template<int EPI, int ORDER>
__global__ __launch_bounds__(512, 1) void gemm_k(const u16* __restrict__ Ab, const u16* __restrict__ Bb,
    int lda, int ldb,
    const float* __restrict__ fp0, void* __restrict__ vp1, void* __restrict__ vp2, void* __restrict__ vp3)
{
  __shared__ u16 L[8][8192];   // [slot*4 + {A0,A1,B0,B1}] of [256 rows][32 k] bf16
  const int tid = threadIdx.x;
  const int lane = tid & 63;
  const int wid = tid >> 6;
  const int wr = wid >> 2, wc = wid & 3;

  const int gx = gridDim.x, gy = gridDim.y;
  const int nwg = gx*gy;
  int lin = (ORDER == 0) ? ((int)blockIdx.x + gx*(int)blockIdx.y)
                         : ((int)blockIdx.y + gy*(int)blockIdx.x);
  const int q8 = nwg >> 3, r8 = nwg & 7;
  const int xcd = lin & 7, base8 = lin >> 3;
  int wg = (xcd < r8 ? xcd*(q8+1) : r8*(q8+1) + (xcd-r8)*q8) + base8;
  int bx, by;
  if (ORDER == 0){ bx = wg % gx; by = wg / gx; }
  else           { by = wg % gy; bx = wg / gy; }

  const u16* A  = Ab + (long long)by*256*lda;
  const u16* Bp = Bb + (long long)bx*256*ldb;

  const int q1 = tid + 512;
  const int q0c = (((tid & 3) ^ ((tid >> 3) & 3)) << 3);
  const int q1c = (((q1  & 3) ^ ((q1  >> 3) & 3)) << 3);
  const u16* gA0 = A  + (long long)(tid >> 2)*lda + q0c;
  const u16* gA1 = A  + (long long)(q1  >> 2)*lda + q1c;
  const u16* gB0 = Bp + (long long)(tid >> 2)*ldb + q0c;
  const u16* gB1 = Bp + (long long)(q1  >> 2)*ldb + q1c;

  auto stageA = [&](int t, int kh){
    u16* d = &L[(t & 1)*4 + kh][0];
    const int k0 = t*64 + kh*32;
    gload16(gA0 + k0, d + tid*8);
    gload16(gA1 + k0, d + q1*8);
  };
  auto stageB = [&](int t, int kh){
    u16* d = &L[(t & 1)*4 + 2 + kh][0];
    const int k0 = t*64 + kh*32;
    gload16(gB0 + k0, d + tid*8);
    gload16(gB1 + k0, d + q1*8);
  };

  int offa[8], offb[4];
  #pragma unroll
  for (int m = 0; m < 8; m++){
    int row = wr*128 + m*16 + (lane & 15);
    offa[m] = row*32 + ((((lane >> 4) ^ (row >> 1)) & 3) << 3);
  }
  #pragma unroll
  for (int n = 0; n < 4; n++){
    int row = wc*64 + n*16 + (lane & 15);
    offb[n] = row*32 + ((((lane >> 4) ^ (row >> 1)) & 3) << 3);
  }

  f32x4 acc[8][4];
  #pragma unroll
  for (int m = 0; m < 8; m++)
    #pragma unroll
    for (int n = 0; n < 4; n++) acc[m][n] = f32x4{0.f,0.f,0.f,0.f};

  bf16x8 af[4], bf[4];
  auto loadA = [&](int t, int kh, int mh){
    const u16* Lb = &L[(t & 1)*4 + kh][0];
    af[0] = *(const bf16x8*)&Lb[offa[mh*4 + 0]];
    af[1] = *(const bf16x8*)&Lb[offa[mh*4 + 1]];
    af[2] = *(const bf16x8*)&Lb[offa[mh*4 + 2]];
    af[3] = *(const bf16x8*)&Lb[offa[mh*4 + 3]];
  };
  auto loadB = [&](int t, int kh){
    const u16* Lb = &L[(t & 1)*4 + 2 + kh][0];
    bf[0] = *(const bf16x8*)&Lb[offb[0]];
    bf[1] = *(const bf16x8*)&Lb[offb[1]];
    bf[2] = *(const bf16x8*)&Lb[offb[2]];
    bf[3] = *(const bf16x8*)&Lb[offb[3]];
  };

  stageA(0,0); stageB(0,0); stageA(0,1); stageB(0,1); stageA(1,0); stageB(1,0);
  asm volatile("s_waitcnt vmcnt(8)" ::: "memory");
  __builtin_amdgcn_s_barrier();

  for (int t = 0; t < NKT; ++t){
    // ---- ph1 ----
    loadA(t, 0, 0); loadB(t, 0);
    if (t + 1 < NKT) stageA(t + 1, 1);
    __builtin_amdgcn_s_barrier();
    asm volatile("s_waitcnt lgkmcnt(0)" ::: "memory");
    __builtin_amdgcn_sched_barrier(0);
    __builtin_amdgcn_s_setprio(1);
    #pragma unroll
    for (int i = 0; i < 4; i++)
      #pragma unroll
      for (int n = 0; n < 4; n++)
        acc[i][n] = __builtin_amdgcn_mfma_f32_16x16x32_bf16(af[i], bf[n], acc[i][n], 0, 0, 0);
    __builtin_amdgcn_s_setprio(0);
    __builtin_amdgcn_s_barrier();

    // ---- ph2 ----
    loadA(t, 0, 1);
    if (t + 1 < NKT) stageB(t + 1, 1);
    __builtin_amdgcn_s_barrier();
    asm volatile("s_waitcnt lgkmcnt(0)" ::: "memory");
    __builtin_amdgcn_sched_barrier(0);
    __builtin_amdgcn_s_setprio(1);
    #pragma unroll
    for (int i = 0; i < 4; i++)
      #pragma unroll
      for (int n = 0; n < 4; n++)
        acc[4+i][n] = __builtin_amdgcn_mfma_f32_16x16x32_bf16(af[i], bf[n], acc[4+i][n], 0, 0, 0);
    __builtin_amdgcn_s_setprio(0);
    if (t < NKT-1) asm volatile("s_waitcnt vmcnt(8)" ::: "memory");
    else           asm volatile("s_waitcnt vmcnt(0)" ::: "memory");
    __builtin_amdgcn_s_barrier();

    // ---- ph3 ----
    loadA(t, 1, 0); loadB(t, 1);
    if (t + 2 < NKT) stageA(t + 2, 0);
    __builtin_amdgcn_s_barrier();
    asm volatile("s_waitcnt lgkmcnt(0)" ::: "memory");
    __builtin_amdgcn_sched_barrier(0);
    __builtin_amdgcn_s_setprio(1);
    #pragma unroll
    for (int i = 0; i < 4; i++)
      #pragma unroll
      for (int n = 0; n < 4; n++)
        acc[i][n] = __builtin_amdgcn_mfma_f32_16x16x32_bf16(af[i], bf[n], acc[i][n], 0, 0, 0);
    __builtin_amdgcn_s_setprio(0);
    __builtin_amdgcn_s_barrier();

    // ---- ph4 ----
    loadA(t, 1, 1);
    if (t + 2 < NKT) stageB(t + 2, 0);
    __builtin_amdgcn_s_barrier();
    asm volatile("s_waitcnt lgkmcnt(0)" ::: "memory");
    __builtin_amdgcn_sched_barrier(0);
    __builtin_amdgcn_s_setprio(1);
    #pragma unroll
    for (int i = 0; i < 4; i++)
      #pragma unroll
      for (int n = 0; n < 4; n++)
        acc[4+i][n] = __builtin_amdgcn_mfma_f32_16x16x32_bf16(af[i], bf[n], acc[4+i][n], 0, 0, 0);
    __builtin_amdgcn_s_setprio(0);
    if (t < NKT-2)       asm volatile("s_waitcnt vmcnt(8)" ::: "memory");
    else if (t == NKT-2) asm volatile("s_waitcnt vmcnt(4)" ::: "memory");
    if (t < NKT-1) __builtin_amdgcn_s_barrier();
  }

  const int tm = by*256 + wr*128;
  const int tn = bx*256 + wc*64;

  if constexpr (EPI == 0){
    // ---- coalesced QKV epilogue (per-wave LDS bounce-transpose for Q/K) ----
    __builtin_amdgcn_s_barrier();   // all waves done reading ring -> slots reusable per-wave
    u16* Qn = (u16*)vp1; u16* Kn = (u16*)vp2; u16* Vt = (u16*)vp3;
    u16* W = &L[wid][0];            // this wave's 16 KB bounce buffer
    // T1: Q/K rows -> LDS [tok 64][d 128] (chunk-XOR swizzled); V rows -> direct store
    #pragma unroll
    for (int m = 0; m < 8; m++){
      const int grp0 = tm + m*16;                 // 16-aligned; 1568 is 16-aligned
      const int row0 = grp0 + (lane>>4)*4;
      if (grp0 < 1568){
        const float b0 = fp0[row0], b1 = fp0[row0+1], b2 = fp0[row0+2], b3 = fp0[row0+3];
        const int dl = m*16 + (lane>>4)*4;        // 4-aligned; swz hits bits 3-5 only
        #pragma unroll
        for (int n = 0; n < 4; n++){
          const int tok = n*16 + (lane&15);
          const int ad  = tok*128 + (dl ^ ((tok&7)<<3));
          u32 lo = (u32)f2bf(acc[m][n][0]+b0) | ((u32)f2bf(acc[m][n][1]+b1) << 16);
          u32 hi = (u32)f2bf(acc[m][n][2]+b2) | ((u32)f2bf(acc[m][n][3]+b3) << 16);
          *(u32*)(W + ad)     = lo;
          *(u32*)(W + ad + 2) = hi;
        }
      } else if (row0 < 2352){
        const int seg = row0 / 392;               // 4 or 5 (V)
        const int hh = seg & 1;
        const int dd0 = row0 - seg*392;
        const float b0 = fp0[row0], b1 = fp0[row0+1], b2 = fp0[row0+2], b3 = fp0[row0+3];
        #pragma unroll
        for (int n = 0; n < 4; n++){
          const int col = tn + n*16 + (lane&15);
          const int bb = col >> 10, nn = col & 1023;
          const long long vb = ((long long)(bb*2 + hh)*DHPV + dd0)*1024 + nn;
          Vt[vb        ] = f2bf(acc[m][n][0] + b0);
          Vt[vb + 1024 ] = f2bf(acc[m][n][1] + b1);
          Vt[vb + 2048 ] = f2bf(acc[m][n][2] + b2);
          Vt[vb + 3072 ] = f2bf(acc[m][n][3] + b3);
        }
      }
    }
    // T2: per-token contiguous-d stores (16 B chunks; same-wave LDS is in-order, no barrier)
    const int climit = min(16, max(0, (1568 - tm) >> 3));
    if (climit > 0){
      const int c  = lane & 15;                   // d-chunk (8 u16)
      const int r0 = tm + c*8;                    // 8-aligned; 392k are 8-aligned
      const int seg = min(r0, 1567) / 392;        // 0..3 (clamped for masked lanes)
      const int hh = seg & 1;
      const int d0 = r0 - seg*392;
      u16* dst0 = (seg < 2) ? Qn : Kn;
      #pragma unroll
      for (int tt = 0; tt < 16; tt++){
        const int tok = tt*4 + (lane>>4);
        bf16x8 vv = *(const bf16x8*)(W + tok*128 + ((c*8) ^ ((tok&7)<<3)));
        if (c < climit){
          const int tg = tn + tok;
          const int bb = tg >> 10, nn = tg & 1023;
          *(bf16x8*)(dst0 + ((long long)((bb*2 + hh)*1024 + nn))*DHP + d0) = vv;
        }
      }
    }
  } else {
    #pragma unroll
    for (int m = 0; m < 8; m++){
      #pragma unroll
      for (int n = 0; n < 4; n++){
        #pragma unroll
        for (int i = 0; i < 4; i++){
          const int row = tm + m*16 + (lane>>4)*4 + i;
          const int col = tn + n*16 + (lane&15);
          float v = acc[m][n][i];
          if constexpr (EPI == 4){
            if (col < KP){
              u16 o = 0;
              if (col < 784){
                float f = v + fp0[col];
                f = f * fminf(fmaxf(f + 3.f, 0.f), 6.f) * (1.f/6.f);
                float hv = bf2f(((const u16*)vp1)[(long long)row*KP + col]);
                o = f2bf(hv + f);
              }
              ((u16*)vp2)[(long long)row*KP + col] = o;
            }
          } else {
            if (col < 784){
              ((float*)vp1)[(long long)row*784 + col] = v + fp0[col];
            }
          }
        }
      }
    }
  }
}

extern "C" void kernel_launch(void* const* d_in, const int* in_sizes, int n_in,
                              void* d_out, int out_size, void* d_ws, size_t ws_size,
                              hipStream_t stream)
{
  const float* x     = (const float*)d_in[0];
  const float* ln_w  = (const float*)d_in[1];
  const float* ln_b  = (const float*)d_in[2];
  const float* qkv_w = (const float*)d_in[3];
  const float* qkv_b = (const float*)d_in[4];
  const float* scale = (const float*)d_in[5];
  const float* out_w = (const float*)d_in[6];
  const float* out_b = (const float*)d_in[7];
  const float* ffn_w = (const float*)d_in[8];
  const float* ffn_b = (const float*)d_in[9];

  char* wsp = (char*)d_ws;
  auto alloc = [&](long long bytes)->char*{ char* p = wsp; wsp += (bytes + 255) & ~255LL; return p; };
  u16* XN   = (u16*)alloc((long long)TOK*KP*2);     // LN1 output (aliased as attnout later)
  u16* WQKV = (u16*)alloc((long long)NQKV*KP*2);
  u16* WFF  = (u16*)alloc(1024LL*KP*2);
  u16* WO   = (u16*)alloc(1024LL*KP*2);
  u16* QN   = (u16*)alloc(64LL*1024*DHP*2);         // aliased as h later
  u16* KN   = (u16*)alloc(64LL*1024*DHP*2);         // aliased as s later
  u16* VT   = (u16*)alloc(64LL*DHPV*1024*2);
  float* FQ = (float*)alloc(65536LL*4);
  float* FK = (float*)alloc(65536LL*4);
  u16* ATT = XN;
  u16* H   = QN;
  u16* S   = KN;
  (void)ws_size; (void)in_sizes; (void)n_in; (void)out_size;

  wconv_k<<<dim3(((long long)NQKV*KP + 255)/256), 256, 0, stream>>>(qkv_w, WQKV, 2352, (long long)NQKV*KP);
  wconv_k<<<dim3((1024*KP + 255)/256), 256, 0, stream>>>(ffn_w, WFF, 784, 1024LL*KP);
  wconv_k<<<dim3((1024*KP + 255)/256), 256, 0, stream>>>(out_w, WO,  784, 1024LL*KP);

  // 1) LN1
  ln1_k<<<dim3(TOK), 256, 0, stream>>>(x, ln_w, ln_b, XN);
  // 2) QKV (flipped): [2560,832] @ [32768,832]^T -> Qn,Kn (coalesced), Vt (natural)
  gemm_k<0,0><<<dim3(128, 10, 1), 512, 0, stream>>>(WQKV, XN, KP, KP, qkv_b, QN, KN, VT);
  // 3) l2norm factors (read-only + pad-zero; no Q/K rewrite)
  norm_k<<<dim3(32768), 256, 0, stream>>>(QN, KN, scale, FQ, FK);
  // 4) fused attention -> ATT (applies fq*fk before exp)
  attn_k<<<dim3(512), 512, 0, stream>>>(QN, KN, VT, FQ, FK, ATT);
  // 5) LN2 + hardswish -> h
  ln2hs_k<<<dim3(TOK), 256, 0, stream>>>(ATT, ln_w, ln_b, H);
  // 6) s = h + hardswish(h @ ffn_w^T + ffn_b)
  gemm_k<4,0><<<dim3(4, 128, 1), 512, 0, stream>>>(H, WFF, KP, KP, ffn_b, H, S, nullptr);
  // 7) y = s @ out_w^T + out_b  (fp32 out)
  gemm_k<5,0><<<dim3(4, 128, 1), 512, 0, stream>>>(S, WO, KP, KP, out_b, d_out, nullptr, nullptr);
}

// Round 15
// 661.662 us; speedup vs baseline: 1.1526x; 1.1526x over previous
//
#include <hip/hip_runtime.h>

typedef unsigned short u16;
typedef unsigned int u32;
typedef __attribute__((ext_vector_type(4))) float f32x4;
typedef __attribute__((ext_vector_type(8))) short bf16x8;

#define TOK 32768      // B*N tokens
#define KP  832        // padded 784 (13*64) K-dim
#define NKT 13         // K-tiles of 64
#define DHP 416        // padded 392 (13*32)
#define DHPV 512       // padded 392 rows for V^T
#define NQKV 2560      // padded 2352 (10*256) rows of qkv_w

static __device__ __forceinline__ float bf2f(u16 u){ u32 v = ((u32)u)<<16; return __builtin_bit_cast(float, v); }
static __device__ __forceinline__ u16 f2bf(float f){
  u32 x = __builtin_bit_cast(u32, f);
  u32 r = (x + 0x7fffu + ((x>>16)&1u)) >> 16;   // RNE
  return (u16)r;
}
static __device__ __forceinline__ void gload16(const void* g, void* l){
  __builtin_amdgcn_global_load_lds((const __attribute__((address_space(1))) void*)g,
                                   (__attribute__((address_space(3))) void*)l, 16, 0, 0);
}
static __device__ __forceinline__ float wave_red_sum(float v){
  #pragma unroll
  for (int o = 32; o > 0; o >>= 1) v += __shfl_xor(v, o, 64);
  return v;
}

// ---------------- weight fp32 -> bf16 with zero padding to [*, KP] ----------------
__global__ __launch_bounds__(256) void wconv_k(const float* __restrict__ src, u16* __restrict__ dst,
                                               int srcR, long long total){
  long long i = (long long)blockIdx.x*256 + threadIdx.x;
  if (i >= total) return;
  int r = (int)(i / KP), c = (int)(i % KP);
  float v = (r < srcR && c < 784) ? src[(long long)r*784 + c] : 0.f;
  dst[i] = f2bf(v);
}

// ---------------- LayerNorm(x fp32) -> bf16 padded [TOK, KP] ----------------
__global__ __launch_bounds__(256) void ln1_k(const float* __restrict__ x, const float* __restrict__ w,
                                             const float* __restrict__ b, u16* __restrict__ out){
  const int tid = threadIdx.x;
  const long long row = blockIdx.x;
  const float* xr = x + row*784;
  float v[4]; float s = 0.f, ss = 0.f;
  #pragma unroll
  for (int i = 0; i < 4; i++){ int c = tid + i*256; float t = (c < 784) ? xr[c] : 0.f; v[i] = t; s += t; ss += t*t; }
  __shared__ float red[8];
  s = wave_red_sum(s); ss = wave_red_sum(ss);
  if ((tid & 63) == 0){ red[tid>>6] = s; red[4 + (tid>>6)] = ss; }
  __syncthreads();
  float S  = red[0]+red[1]+red[2]+red[3];
  float SS = red[4]+red[5]+red[6]+red[7];
  float mean = S * (1.f/784.f);
  float var  = SS * (1.f/784.f) - mean*mean;
  float rstd = rsqrtf(var + 1e-5f);
  u16* orow = out + row*KP;
  #pragma unroll
  for (int i = 0; i < 4; i++){
    int c = tid + i*256;
    if (c < KP){
      u16 o = 0;
      if (c < 784) o = f2bf((v[i]-mean)*rstd*w[c] + b[c]);
      orow[c] = o;
    }
  }
}

// ---------------- LayerNorm(attnout bf16) + hardswish -> bf16 padded [TOK, KP] ----------------
__global__ __launch_bounds__(256) void ln2hs_k(const u16* __restrict__ a, const float* __restrict__ w,
                                               const float* __restrict__ b, u16* __restrict__ out){
  const int tid = threadIdx.x;
  const long long row = blockIdx.x;
  const u16* ar = a + row*784;
  float v[4]; float s = 0.f, ss = 0.f;
  #pragma unroll
  for (int i = 0; i < 4; i++){ int c = tid + i*256; float t = (c < 784) ? bf2f(ar[c]) : 0.f; v[i] = t; s += t; ss += t*t; }
  __shared__ float red[8];
  s = wave_red_sum(s); ss = wave_red_sum(ss);
  if ((tid & 63) == 0){ red[tid>>6] = s; red[4 + (tid>>6)] = ss; }
  __syncthreads();
  float S  = red[0]+red[1]+red[2]+red[3];
  float SS = red[4]+red[5]+red[6]+red[7];
  float mean = S * (1.f/784.f);
  float var  = SS * (1.f/784.f) - mean*mean;
  float rstd = rsqrtf(var + 1e-5f);
  u16* orow = out + row*KP;
  #pragma unroll
  for (int i = 0; i < 4; i++){
    int c = tid + i*256;
    if (c < KP){
      u16 o = 0;
      if (c < 784){
        float y = (v[i]-mean)*rstd*w[c] + b[c];
        y = y * fminf(fmaxf(y + 3.f, 0.f), 6.f) * (1.f/6.f);   // hardswish
        o = f2bf(y);
      }
      orow[c] = o;
    }
  }
}

// ---------------- in-place L2-normalize Q (x sqrt(scale)) and K rows, zero pads ----------------
// DHP=416 -> 104 chunks of 4 bf16; chunks 0..97 real (d<392), 98..103 zeroed.
__global__ __launch_bounds__(256) void l2n_k(u16* __restrict__ Q, u16* __restrict__ Kb,
                                             const float* __restrict__ scale){
  const int lane = threadIdx.x & 63, wv = threadIdx.x >> 6;
  const long long rid = (long long)blockIdx.x*4 + wv;     // 131072 rows: Q then K
  const bool isK = rid >= 65536;
  const long long idx = isK ? rid - 65536 : rid;
  u16* base = (isK ? Kb : Q) + idx*DHP;
  uint2 t0 = *(const uint2*)(base + lane*4);
  int ch1 = lane + 64;
  uint2 t1 = (ch1 < 104) ? *(const uint2*)(base + ch1*4) : make_uint2(0u,0u);
  float f0[4], f1[4];
  u32 c0[2] = {t0.x, t0.y}, c1[2] = {t1.x, t1.y};
  #pragma unroll
  for (int j = 0; j < 4; j++){
    f0[j] = bf2f((u16)(c0[j>>1] >> ((j&1)*16)));
    f1[j] = bf2f((u16)(c1[j>>1] >> ((j&1)*16)));
  }
  float ssq = 0.f;
  #pragma unroll
  for (int j = 0; j < 4; j++) ssq += f0[j]*f0[j];
  if (ch1 < 98){
    #pragma unroll
    for (int j = 0; j < 4; j++) ssq += f1[j]*f1[j];
  }
  ssq = wave_red_sum(ssq);
  float fac = 1.f / fmaxf(sqrtf(ssq), 1e-12f);
  if (!isK) fac *= sqrtf(scale[(int)((idx >> 10) & 1)]);   // fold sqrt(scale[h]) into q
  u32 o0[2], o1[2];
  #pragma unroll
  for (int j = 0; j < 2; j++){
    u16 lo = f2bf(f0[2*j]*fac),   hi = f2bf(f0[2*j+1]*fac);
    o0[j] = (u32)lo | ((u32)hi << 16);
    u16 lo1 = (ch1 < 98) ? f2bf(f1[2*j]*fac)   : (u16)0;
    u16 hi1 = (ch1 < 98) ? f2bf(f1[2*j+1]*fac) : (u16)0;
    o1[j] = (u32)lo1 | ((u32)hi1 << 16);
  }
  *(uint2*)(base + lane*4) = make_uint2(o0[0], o0[1]);
  if (ch1 < 104) *(uint2*)(base + ch1*4) = make_uint2(o1[0], o1[1]);
}

// =======================================================================================
// Fused attention v5 (best-known): 80 KB LDS (2 blocks/CU). Phase A 13 K-steps.
// LDS staging retained: K/V lines fetched once per block, shared across 8 waves (R12
// showed de-staging multiplies L2 traffic 4x; R14 showed factor-gathers in the
// transition cost more than the separate l2n pass).
// =======================================================================================
__global__ __launch_bounds__(512, 2) void attn_k(const u16* __restrict__ Qb, const u16* __restrict__ Kb,
    const u16* __restrict__ Vtb, u16* __restrict__ att)
{
  __shared__ u16 smem[40960];      // slots 0..2 at 0/8192/16384 (16 KB each); Pbuf at 24576 (32 KB)
  u16* Pbuf = smem + 24576;

  const int tid = threadIdx.x, lane = tid & 63, wid = tid >> 6;
  const int wq  = wid >> 2, kvw = wid & 3;     // phase A: 2 q-halves(64) x 4 kv(32)
  const int dw  = wid >> 2, qw  = wid & 3;     // phase B: 2 d(112) x 4 q(32)

  const int lin = (int)blockIdx.x;
  const int bh = (lin & 7)*8 + (lin >> 6);
  const int qt = (lin >> 3) & 7;

  const u16* Qp = Qb  + ((long long)bh*1024 + (long long)qt*128)*DHP;
  const u16* Kp = Kb  + (long long)bh*1024*DHP;
  const u16* Vp = Vtb + (long long)bh*DHPV*1024;

  const int srow = tid >> 2;
  const int scol = (((tid & 3) ^ ((srow >> 1) & 3)) << 3);
  const int s2   = tid + 512;
  const int r2   = s2 >> 2;
  const int c2   = (((s2 & 3) ^ ((r2 >> 1) & 3)) << 3);

  int offq[4], offk[2], offv[7];
  #pragma unroll
  for (int m = 0; m < 4; m++){
    int r = wq*64 + m*16 + (lane & 15);
    offq[m] = r*32 + ((((lane>>4) ^ (r>>1)) & 3) << 3);
  }
  #pragma unroll
  for (int n = 0; n < 2; n++){
    int r = kvw*32 + n*16 + (lane & 15);
    offk[n] = 4096 + r*32 + ((((lane>>4) ^ (r>>1)) & 3) << 3);
  }
  #pragma unroll
  for (int m = 0; m < 7; m++){
    int r = dw*112 + m*16 + (lane & 15);
    offv[m] = r*32 + ((((lane>>4) ^ (r>>1)) & 3) << 3);
  }

  auto stageA = [&](int ck, int t, int buf){
    u16* rb = smem + buf*8192;
    gload16(Qp + (long long)srow*DHP + t*32 + scol,            rb + tid*8);
    gload16(Kp + (long long)(ck*128 + srow)*DHP + t*32 + scol, rb + 4096 + tid*8);
  };
  auto stageV = [&](int ck, int ms, int buf){
    u16* rb = smem + buf*8192;
    const int h = ms >> 2, s = ms & 3;
    const u16* src = Vp + (long long)(h*224)*1024 + ck*128 + s*32;
    gload16(src + (long long)srow*1024 + scol, rb + tid*8);
    gload16(src + (long long)r2*1024  + c2,   rb + s2*8);
  };

  f32x4 oacc[2][7][2];
  #pragma unroll
  for (int h = 0; h < 2; h++)
    #pragma unroll
    for (int m = 0; m < 7; m++)
      #pragma unroll
      for (int n = 0; n < 2; n++) oacc[h][m][n] = f32x4{0.f,0.f,0.f,0.f};
  float rs_r[16];
  #pragma unroll
  for (int i = 0; i < 16; i++) rs_r[i] = 0.f;

  for (int ck = 0; ck < 8; ++ck){
    // ---------------- phase A: S = Q @ K^T (13 steps, ring-3, lookahead-2) ----------------
    stageA(ck, 0, 0); stageA(ck, 1, 1);
    asm volatile("s_waitcnt vmcnt(2)" ::: "memory");
    __builtin_amdgcn_s_barrier();
    f32x4 sacc[4][2];
    #pragma unroll
    for (int m = 0; m < 4; m++)
      #pragma unroll
      for (int n = 0; n < 2; n++) sacc[m][n] = f32x4{0.f,0.f,0.f,0.f};

    for (int t = 0; t < 13; ++t){
      if (t + 2 < 13) stageA(ck, t+2, (t+2)%3);
      const u16* ra = smem + (t%3)*8192;
      bf16x8 aq[4], bk[2];
      #pragma unroll
      for (int m = 0; m < 4; m++) aq[m] = *(const bf16x8*)(ra + offq[m]);
      #pragma unroll
      for (int n = 0; n < 2; n++) bk[n] = *(const bf16x8*)(ra + offk[n]);
      __builtin_amdgcn_s_setprio(1);
      #pragma unroll
      for (int m = 0; m < 4; m++)
        #pragma unroll
        for (int n = 0; n < 2; n++)
          sacc[m][n] = __builtin_amdgcn_mfma_f32_16x16x32_bf16(aq[m], bk[n], sacc[m][n], 0, 0, 0);
      __builtin_amdgcn_s_setprio(0);
      if (t + 2 < 13)      asm volatile("s_waitcnt vmcnt(2)" ::: "memory");
      else if (t + 1 < 13) asm volatile("s_waitcnt vmcnt(0)" ::: "memory");
      if (t + 1 < 13) __builtin_amdgcn_s_barrier();
    }
    __builtin_amdgcn_s_barrier();   // all waves done reading ring

    // -------- transition: issue V0,V1 stages, then P = exp(S) -> Pbuf + rowsum --------
    stageV(ck, 0, 0); stageV(ck, 1, 1);
    #pragma unroll
    for (int m = 0; m < 4; m++){
      #pragma unroll
      for (int i = 0; i < 4; i++){
        const int q = wq*64 + m*16 + (lane>>4)*4 + i;
        float a = 0.f;
        #pragma unroll
        for (int n = 0; n < 2; n++){
          const int kv = kvw*32 + n*16 + (lane & 15);
          u16 pb = f2bf(__expf(sacc[m][n][i]));
          Pbuf[q*128 + (((kv>>3) ^ (q&15)) << 3) + (kv&7)] = pb;
          a += bf2f(pb);
        }
        rs_r[m*4+i] += a;
      }
    }
    asm volatile("s_waitcnt vmcnt(2) lgkmcnt(0)" ::: "memory");   // V0 ready, P visible
    __builtin_amdgcn_s_barrier();

    // ---------------- phase B: O^T += VT @ P^T (8 steps, ring-3, lookahead-2) ----------------
    #pragma unroll
    for (int ms = 0; ms < 8; ++ms){
      if (ms + 2 < 8) stageV(ck, ms+2, (ms+2)%3);
      const u16* vb = smem + (ms%3)*8192;
      const int s = ms & 3;
      const int h = ms >> 2;
      bf16x8 av[7], bp[2];
      #pragma unroll
      for (int m = 0; m < 7; m++) av[m] = *(const bf16x8*)(vb + offv[m]);
      #pragma unroll
      for (int n = 0; n < 2; n++){
        const int q = qw*32 + n*16 + (lane & 15);
        const int cc = s*4 + (lane>>4);
        bp[n] = *(const bf16x8*)(Pbuf + q*128 + ((cc ^ (q&15)) << 3));
      }
      __builtin_amdgcn_s_setprio(1);
      #pragma unroll
      for (int m = 0; m < 7; m++)
        #pragma unroll
        for (int n = 0; n < 2; n++)
          oacc[h][m][n] = __builtin_amdgcn_mfma_f32_16x16x32_bf16(av[m], bp[n], oacc[h][m][n], 0, 0, 0);
      __builtin_amdgcn_s_setprio(0);
      if (ms + 2 < 8)      asm volatile("s_waitcnt vmcnt(2)" ::: "memory");
      else if (ms + 1 < 8) asm volatile("s_waitcnt vmcnt(0)" ::: "memory");
      if (ms + 1 < 8) __builtin_amdgcn_s_barrier();
    }
    __builtin_amdgcn_s_barrier();   // ring + Pbuf free before next chunk's phase A
  }

  float* rsL = (float*)&smem[0];   // [128][4]
  float* rsT = rsL + 512;          // [128]
  #pragma unroll
  for (int m = 0; m < 4; m++){
    #pragma unroll
    for (int i = 0; i < 4; i++){
      float v = rs_r[m*4+i];
      v += __shfl_xor(v, 1, 64); v += __shfl_xor(v, 2, 64);
      v += __shfl_xor(v, 4, 64); v += __shfl_xor(v, 8, 64);
      if ((lane & 15) == 0) rsL[(wq*64 + m*16 + (lane>>4)*4 + i)*4 + kvw] = v;
    }
  }
  __syncthreads();
  if (tid < 128) rsT[tid] = 1.f/(rsL[tid*4]+rsL[tid*4+1]+rsL[tid*4+2]+rsL[tid*4+3]);
  __syncthreads();
  const int b = bh >> 1, hh = bh & 1;
  #pragma unroll
  for (int h = 0; h < 2; h++){
    #pragma unroll
    for (int n = 0; n < 2; n++){
      const int q = qw*32 + n*16 + (lane & 15);
      const float rinv = rsT[q];
      u16* arw = att + ((long long)(b*1024 + qt*128 + q))*784 + hh*392;
      #pragma unroll
      for (int m = 0; m < 7; m++){
        const int d0 = h*224 + dw*112 + m*16 + (lane>>4)*4;
        if (d0 < 392){
          u16 a0 = f2bf(oacc[h][m][n][0]*rinv), a1 = f2bf(oacc[h][m][n][1]*rinv);
          u16 a2 = f2bf(oacc[h][m][n][2]*rinv), a3 = f2bf(oacc[h][m][n][3]*rinv);
          *(u32*)(arw + d0)     = (u32)a0 | ((u32)a1 << 16);
          *(u32*)(arw + d0 + 2) = (u32)a2 | ((u32)a3 << 16);
        }
      }
    }
  }
}

// =======================================================================================
// GEMM v7 (best-known): 4-phase K-split loop + coalesced QKV epilogue.
// EPI 0: QKV  4: FFN+hs+residual  5: fp32 out
// =======================================================================================
template<int EPI, int ORDER>
__global__ __launch_bounds__(512, 1) void gemm_k(const u16* __restrict__ Ab, const u16* __restrict__ Bb,
    int lda, int ldb,
    const float* __restrict__ fp0, void* __restrict__ vp1, void* __restrict__ vp2, void* __restrict__ vp3)
{
  __shared__ u16 L[8][8192];   // [slot*4 + {A0,A1,B0,B1}] of [256 rows][32 k] bf16
  const int tid = threadIdx.x;
  const int lane = tid & 63;
  const int wid = tid >> 6;
  const int wr = wid >> 2, wc = wid & 3;

  const int gx = gridDim.x, gy = gridDim.y;
  const int nwg = gx*gy;
  int lin = (ORDER == 0) ? ((int)blockIdx.x + gx*(int)blockIdx.y)
                         : ((int)blockIdx.y + gy*(int)blockIdx.x);
  const int q8 = nwg >> 3, r8 = nwg & 7;
  const int xcd = lin & 7, base8 = lin >> 3;
  int wg = (xcd < r8 ? xcd*(q8+1) : r8*(q8+1) + (xcd-r8)*q8) + base8;
  int bx, by;
  if (ORDER == 0){ bx = wg % gx; by = wg / gx; }
  else           { by = wg % gy; bx = wg / gy; }

  const u16* A  = Ab + (long long)by*256*lda;
  const u16* Bp = Bb + (long long)bx*256*ldb;

  const int q1 = tid + 512;
  const int q0c = (((tid & 3) ^ ((tid >> 3) & 3)) << 3);
  const int q1c = (((q1  & 3) ^ ((q1  >> 3) & 3)) << 3);
  const u16* gA0 = A  + (long long)(tid >> 2)*lda + q0c;
  const u16* gA1 = A  + (long long)(q1  >> 2)*lda + q1c;
  const u16* gB0 = Bp + (long long)(tid >> 2)*ldb + q0c;
  const u16* gB1 = Bp + (long long)(q1  >> 2)*ldb + q1c;

  auto stageA = [&](int t, int kh){
    u16* d = &L[(t & 1)*4 + kh][0];
    const int k0 = t*64 + kh*32;
    gload16(gA0 + k0, d + tid*8);
    gload16(gA1 + k0, d + q1*8);
  };
  auto stageB = [&](int t, int kh){
    u16* d = &L[(t & 1)*4 + 2 + kh][0];
    const int k0 = t*64 + kh*32;
    gload16(gB0 + k0, d + tid*8);
    gload16(gB1 + k0, d + q1*8);
  };

  int offa[8], offb[4];
  #pragma unroll
  for (int m = 0; m < 8; m++){
    int row = wr*128 + m*16 + (lane & 15);
    offa[m] = row*32 + ((((lane >> 4) ^ (row >> 1)) & 3) << 3);
  }
  #pragma unroll
  for (int n = 0; n < 4; n++){
    int row = wc*64 + n*16 + (lane & 15);
    offb[n] = row*32 + ((((lane >> 4) ^ (row >> 1)) & 3) << 3);
  }

  f32x4 acc[8][4];
  #pragma unroll
  for (int m = 0; m < 8; m++)
    #pragma unroll
    for (int n = 0; n < 4; n++) acc[m][n] = f32x4{0.f,0.f,0.f,0.f};

  bf16x8 af[4], bf[4];
  auto loadA = [&](int t, int kh, int mh){
    const u16* Lb = &L[(t & 1)*4 + kh][0];
    af[0] = *(const bf16x8*)&Lb[offa[mh*4 + 0]];
    af[1] = *(const bf16x8*)&Lb[offa[mh*4 + 1]];
    af[2] = *(const bf16x8*)&Lb[offa[mh*4 + 2]];
    af[3] = *(const bf16x8*)&Lb[offa[mh*4 + 3]];
  };
  auto loadB = [&](int t, int kh){
    const u16* Lb = &L[(t & 1)*4 + 2 + kh][0];
    bf[0] = *(const bf16x8*)&Lb[offb[0]];
    bf[1] = *(const bf16x8*)&Lb[offb[1]];
    bf[2] = *(const bf16x8*)&Lb[offb[2]];
    bf[3] = *(const bf16x8*)&Lb[offb[3]];
  };

  stageA(0,0); stageB(0,0); stageA(0,1); stageB(0,1); stageA(1,0); stageB(1,0);
  asm volatile("s_waitcnt vmcnt(8)" ::: "memory");
  __builtin_amdgcn_s_barrier();

  for (int t = 0; t < NKT; ++t){
    // ---- ph1 ----
    loadA(t, 0, 0); loadB(t, 0);
    if (t + 1 < NKT) stageA(t + 1, 1);
    __builtin_amdgcn_s_barrier();
    asm volatile("s_waitcnt lgkmcnt(0)" ::: "memory");
    __builtin_amdgcn_sched_barrier(0);
    __builtin_amdgcn_s_setprio(1);
    #pragma unroll
    for (int i = 0; i < 4; i++)
      #pragma unroll
      for (int n = 0; n < 4; n++)
        acc[i][n] = __builtin_amdgcn_mfma_f32_16x16x32_bf16(af[i], bf[n], acc[i][n], 0, 0, 0);
    __builtin_amdgcn_s_setprio(0);
    __builtin_amdgcn_s_barrier();

    // ---- ph2 ----
    loadA(t, 0, 1);
    if (t + 1 < NKT) stageB(t + 1, 1);
    __builtin_amdgcn_s_barrier();
    asm volatile("s_waitcnt lgkmcnt(0)" ::: "memory");
    __builtin_amdgcn_sched_barrier(0);
    __builtin_amdgcn_s_setprio(1);
    #pragma unroll
    for (int i = 0; i < 4; i++)
      #pragma unroll
      for (int n = 0; n < 4; n++)
        acc[4+i][n] = __builtin_amdgcn_mfma_f32_16x16x32_bf16(af[i], bf[n], acc[4+i][n], 0, 0, 0);
    __builtin_amdgcn_s_setprio(0);
    if (t < NKT-1) asm volatile("s_waitcnt vmcnt(8)" ::: "memory");
    else           asm volatile("s_waitcnt vmcnt(0)" ::: "memory");
    __builtin_amdgcn_s_barrier();

    // ---- ph3 ----
    loadA(t, 1, 0); loadB(t, 1);
    if (t + 2 < NKT) stageA(t + 2, 0);
    __builtin_amdgcn_s_barrier();
    asm volatile("s_waitcnt lgkmcnt(0)" ::: "memory");
    __builtin_amdgcn_sched_barrier(0);
    __builtin_amdgcn_s_setprio(1);
    #pragma unroll
    for (int i = 0; i < 4; i++)
      #pragma unroll
      for (int n = 0; n < 4; n++)
        acc[i][n] = __builtin_amdgcn_mfma_f32_16x16x32_bf16(af[i], bf[n], acc[i][n], 0, 0, 0);
    __builtin_amdgcn_s_setprio(0);
    __builtin_amdgcn_s_barrier();

    // ---- ph4 ----
    loadA(t, 1, 1);
    if (t + 2 < NKT) stageB(t + 2, 0);
    __builtin_amdgcn_s_barrier();
    asm volatile("s_waitcnt lgkmcnt(0)" ::: "memory");
    __builtin_amdgcn_sched_barrier(0);
    __builtin_amdgcn_s_setprio(1);
    #pragma unroll
    for (int i = 0; i < 4; i++)
      #pragma unroll
      for (int n = 0; n < 4; n++)
        acc[4+i][n] = __builtin_amdgcn_mfma_f32_16x16x32_bf16(af[i], bf[n], acc[4+i][n], 0, 0, 0);
    __builtin_amdgcn_s_setprio(0);
    if (t < NKT-2)       asm volatile("s_waitcnt vmcnt(8)" ::: "memory");
    else if (t == NKT-2) asm volatile("s_waitcnt vmcnt(4)" ::: "memory");
    if (t < NKT-1) __builtin_amdgcn_s_barrier();
  }

  const int tm = by*256 + wr*128;
  const int tn = bx*256 + wc*64;

  if constexpr (EPI == 0){
    // ---- coalesced QKV epilogue (per-wave LDS bounce-transpose for Q/K) ----
    __builtin_amdgcn_s_barrier();   // all waves done reading ring -> slots reusable per-wave
    u16* Qn = (u16*)vp1; u16* Kn = (u16*)vp2; u16* Vt = (u16*)vp3;
    u16* W = &L[wid][0];            // this wave's 16 KB bounce buffer
    // T1: Q/K rows -> LDS [tok 64][d 128] (chunk-XOR swizzled); V rows -> direct store
    #pragma unroll
    for (int m = 0; m < 8; m++){
      const int grp0 = tm + m*16;                 // 16-aligned; 1568 is 16-aligned
      const int row0 = grp0 + (lane>>4)*4;
      if (grp0 < 1568){
        const float b0 = fp0[row0], b1 = fp0[row0+1], b2 = fp0[row0+2], b3 = fp0[row0+3];
        const int dl = m*16 + (lane>>4)*4;        // 4-aligned; swz hits bits 3-5 only
        #pragma unroll
        for (int n = 0; n < 4; n++){
          const int tok = n*16 + (lane&15);
          const int ad  = tok*128 + (dl ^ ((tok&7)<<3));
          u32 lo = (u32)f2bf(acc[m][n][0]+b0) | ((u32)f2bf(acc[m][n][1]+b1) << 16);
          u32 hi = (u32)f2bf(acc[m][n][2]+b2) | ((u32)f2bf(acc[m][n][3]+b3) << 16);
          *(u32*)(W + ad)     = lo;
          *(u32*)(W + ad + 2) = hi;
        }
      } else if (row0 < 2352){
        const int seg = row0 / 392;               // 4 or 5 (V)
        const int hh = seg & 1;
        const int dd0 = row0 - seg*392;
        const float b0 = fp0[row0], b1 = fp0[row0+1], b2 = fp0[row0+2], b3 = fp0[row0+3];
        #pragma unroll
        for (int n = 0; n < 4; n++){
          const int col = tn + n*16 + (lane&15);
          const int bb = col >> 10, nn = col & 1023;
          const long long vb = ((long long)(bb*2 + hh)*DHPV + dd0)*1024 + nn;
          Vt[vb        ] = f2bf(acc[m][n][0] + b0);
          Vt[vb + 1024 ] = f2bf(acc[m][n][1] + b1);
          Vt[vb + 2048 ] = f2bf(acc[m][n][2] + b2);
          Vt[vb + 3072 ] = f2bf(acc[m][n][3] + b3);
        }
      }
    }
    // T2: per-token contiguous-d stores (16 B chunks; same-wave LDS is in-order, no barrier)
    const int climit = min(16, max(0, (1568 - tm) >> 3));
    if (climit > 0){
      const int c  = lane & 15;                   // d-chunk (8 u16)
      const int r0 = tm + c*8;                    // 8-aligned; 392k are 8-aligned
      const int seg = min(r0, 1567) / 392;        // 0..3 (clamped for masked lanes)
      const int hh = seg & 1;
      const int d0 = r0 - seg*392;
      u16* dst0 = (seg < 2) ? Qn : Kn;
      #pragma unroll
      for (int tt = 0; tt < 16; tt++){
        const int tok = tt*4 + (lane>>4);
        bf16x8 vv = *(const bf16x8*)(W + tok*128 + ((c*8) ^ ((tok&7)<<3)));
        if (c < climit){
          const int tg = tn + tok;
          const int bb = tg >> 10, nn = tg & 1023;
          *(bf16x8*)(dst0 + ((long long)((bb*2 + hh)*1024 + nn))*DHP + d0) = vv;
        }
      }
    }
  } else {
    #pragma unroll
    for (int m = 0; m < 8; m++){
      #pragma unroll
      for (int n = 0; n < 4; n++){
        #pragma unroll
        for (int i = 0; i < 4; i++){
          const int row = tm + m*16 + (lane>>4)*4 + i;
          const int col = tn + n*16 + (lane&15);
          float v = acc[m][n][i];
          if constexpr (EPI == 4){
            if (col < KP){
              u16 o = 0;
              if (col < 784){
                float f = v + fp0[col];
                f = f * fminf(fmaxf(f + 3.f, 0.f), 6.f) * (1.f/6.f);
                float hv = bf2f(((const u16*)vp1)[(long long)row*KP + col]);
                o = f2bf(hv + f);
              }
              ((u16*)vp2)[(long long)row*KP + col] = o;
            }
          } else {
            if (col < 784){
              ((float*)vp1)[(long long)row*784 + col] = v + fp0[col];
            }
          }
        }
      }
    }
  }
}

extern "C" void kernel_launch(void* const* d_in, const int* in_sizes, int n_in,
                              void* d_out, int out_size, void* d_ws, size_t ws_size,
                              hipStream_t stream)
{
  const float* x     = (const float*)d_in[0];
  const float* ln_w  = (const float*)d_in[1];
  const float* ln_b  = (const float*)d_in[2];
  const float* qkv_w = (const float*)d_in[3];
  const float* qkv_b = (const float*)d_in[4];
  const float* scale = (const float*)d_in[5];
  const float* out_w = (const float*)d_in[6];
  const float* out_b = (const float*)d_in[7];
  const float* ffn_w = (const float*)d_in[8];
  const float* ffn_b = (const float*)d_in[9];

  char* wsp = (char*)d_ws;
  auto alloc = [&](long long bytes)->char*{ char* p = wsp; wsp += (bytes + 255) & ~255LL; return p; };
  u16* XN   = (u16*)alloc((long long)TOK*KP*2);     // LN1 output (aliased as attnout later)
  u16* WQKV = (u16*)alloc((long long)NQKV*KP*2);
  u16* WFF  = (u16*)alloc(1024LL*KP*2);
  u16* WO   = (u16*)alloc(1024LL*KP*2);
  u16* QN   = (u16*)alloc(64LL*1024*DHP*2);         // aliased as h later
  u16* KN   = (u16*)alloc(64LL*1024*DHP*2);         // aliased as s later
  u16* VT   = (u16*)alloc(64LL*DHPV*1024*2);
  u16* ATT = XN;
  u16* H   = QN;
  u16* S   = KN;
  (void)ws_size; (void)in_sizes; (void)n_in; (void)out_size;

  wconv_k<<<dim3(((long long)NQKV*KP + 255)/256), 256, 0, stream>>>(qkv_w, WQKV, 2352, (long long)NQKV*KP);
  wconv_k<<<dim3((1024*KP + 255)/256), 256, 0, stream>>>(ffn_w, WFF, 784, 1024LL*KP);
  wconv_k<<<dim3((1024*KP + 255)/256), 256, 0, stream>>>(out_w, WO,  784, 1024LL*KP);

  // 1) LN1
  ln1_k<<<dim3(TOK), 256, 0, stream>>>(x, ln_w, ln_b, XN);
  // 2) QKV (flipped): [2560,832] @ [32768,832]^T -> Qn,Kn (coalesced), Vt (natural)
  gemm_k<0,0><<<dim3(128, 10, 1), 512, 0, stream>>>(WQKV, XN, KP, KP, qkv_b, QN, KN, VT);
  // 3) l2norm q (x sqrt(scale)), k
  l2n_k<<<dim3(32768), 256, 0, stream>>>(QN, KN, scale);
  // 4) fused attention -> ATT
  attn_k<<<dim3(512), 512, 0, stream>>>(QN, KN, VT, ATT);
  // 5) LN2 + hardswish -> h
  ln2hs_k<<<dim3(TOK), 256, 0, stream>>>(ATT, ln_w, ln_b, H);
  // 6) s = h + hardswish(h @ ffn_w^T + ffn_b)
  gemm_k<4,0><<<dim3(4, 128, 1), 512, 0, stream>>>(H, WFF, KP, KP, ffn_b, H, S, nullptr);
  // 7) y = s @ out_w^T + out_b  (fp32 out)
  gemm_k<5,0><<<dim3(4, 128, 1), 512, 0, stream>>>(S, WO, KP, KP, out_b, d_out, nullptr, nullptr);
}